// Round 1
// baseline (7368.462 us; speedup 1.0000x reference)
//
#include <hip/hip_runtime.h>
#include <hip/hip_bf16.h>
#include <math.h>

typedef __attribute__((ext_vector_type(8))) short short8;
typedef __attribute__((ext_vector_type(4))) float f32x4;

constexpr int Bc = 4, Tc = 2048, Dc = 1024, Nheads = 16, Hc = 64, Fc = 4096;
constexpr int Mrows = Bc * Tc;          // 8192
constexpr float SOFTCAP = 50.0f;
constexpr float LNEPS = 1e-6f;

__device__ __forceinline__ float bf2f(__hip_bfloat16 x) { return __bfloat162float(x); }

__device__ __forceinline__ float gelu_exact(float x) {
    return 0.5f * x * (1.0f + erff(x * 0.70710678118654752440f));
}

// ---------- fp32 [K,N] -> bf16 [N,K] transpose+convert ----------
__global__ __launch_bounds__(256) void transpose_cvt(const float* __restrict__ src,
                                                     __hip_bfloat16* __restrict__ dst,
                                                     int K, int N) {
    __shared__ float tile[32][33];
    const int n0 = blockIdx.x * 32, k0 = blockIdx.y * 32;
    const int tx = threadIdx.x & 31, ty = threadIdx.x >> 5;   // 32 x 8
    #pragma unroll
    for (int i = 0; i < 32; i += 8)
        tile[ty + i][tx] = src[(size_t)(k0 + ty + i) * N + (n0 + tx)];
    __syncthreads();
    #pragma unroll
    for (int i = 0; i < 32; i += 8)
        dst[(size_t)(n0 + ty + i) * K + (k0 + tx)] = __float2bfloat16(tile[tx][ty + i]);
}

// ---------- concat bq,bk,bv -> [3072] ----------
__global__ void concat_bias(const float* __restrict__ bq, const float* __restrict__ bk,
                            const float* __restrict__ bv, float* __restrict__ dst) {
    int i = blockIdx.x * 256 + threadIdx.x;   // 3072 total
    float v = (i < 1024) ? bq[i] : (i < 2048 ? bk[i - 1024] : bv[i - 2048]);
    dst[i] = v;
}

// ---------- LayerNorm fp32 -> bf16 ----------
__global__ __launch_bounds__(256) void ln_kernel(const float* __restrict__ x,
                                                 const float* __restrict__ gamma,
                                                 const float* __restrict__ beta,
                                                 __hip_bfloat16* __restrict__ out) {
    __shared__ float2 red[4];
    const int row = blockIdx.x, tid = threadIdx.x;
    const float* xr = x + (size_t)row * Dc;
    float4 v = ((const float4*)xr)[tid];
    float s  = v.x + v.y + v.z + v.w;
    float ss = v.x * v.x + v.y * v.y + v.z * v.z + v.w * v.w;
    #pragma unroll
    for (int o = 32; o; o >>= 1) { s += __shfl_down(s, o, 64); ss += __shfl_down(ss, o, 64); }
    if ((tid & 63) == 0) red[tid >> 6] = make_float2(s, ss);
    __syncthreads();
    float2 r0 = red[0], r1 = red[1], r2 = red[2], r3 = red[3];
    s  = r0.x + r1.x + r2.x + r3.x;
    ss = r0.y + r1.y + r2.y + r3.y;
    const float mean = s * (1.0f / Dc);
    const float var  = ss * (1.0f / Dc) - mean * mean;
    const float inv  = rsqrtf(var + LNEPS);
    float4 g  = ((const float4*)gamma)[tid];
    float4 bb = ((const float4*)beta)[tid];
    __hip_bfloat16* orow = out + (size_t)row * Dc + tid * 4;
    orow[0] = __float2bfloat16((v.x - mean) * inv * g.x + bb.x);
    orow[1] = __float2bfloat16((v.y - mean) * inv * g.y + bb.y);
    orow[2] = __float2bfloat16((v.z - mean) * inv * g.z + bb.z);
    orow[3] = __float2bfloat16((v.w - mean) * inv * g.w + bb.w);
}

// ---------- bf16 MFMA GEMM: C[M,N] = A[M,K] * Bt[N,K]^T + bias (+gelu | +resid) ----------
// EPI: 0 = bias only, 1 = bias+gelu, 2 = bias+fp32-residual
template <int EPI, bool OUT_BF16>
__global__ __launch_bounds__(256) void gemm_kernel(
    const __hip_bfloat16* __restrict__ A, const __hip_bfloat16* __restrict__ Bt,
    const float* __restrict__ bias, const float* __restrict__ resid,
    void* __restrict__ Cout, int M, int N, int K) {
    // LDS row stride 40 elems = 80 B: 16B-aligned for b128, 2-way-bank (free)
    __shared__ __align__(16) __hip_bfloat16 As[128 * 40];
    __shared__ __align__(16) __hip_bfloat16 Bs[128 * 40];
    const int tid = threadIdx.x;
    const int wave = tid >> 6, lane = tid & 63, quad = lane >> 4, l16 = lane & 15;
    const int m0 = blockIdx.x * 128, n0 = blockIdx.y * 128;
    const int wm = (wave >> 1) * 64, wn = (wave & 1) * 64;
    const int ar = tid >> 2, ac = (tid & 3) * 8;
    f32x4 acc[4][4] = {};

    const size_t aBase = (size_t)(m0 + ar) * K + ac;
    const size_t bBase = (size_t)(n0 + ar) * K + ac;
    for (int k0 = 0; k0 < K; k0 += 32) {
        *(short8*)&As[ar * 40 + ac]        = *(const short8*)&A[aBase + k0];
        *(short8*)&As[(ar + 64) * 40 + ac] = *(const short8*)&A[aBase + (size_t)64 * K + k0];
        *(short8*)&Bs[ar * 40 + ac]        = *(const short8*)&Bt[bBase + k0];
        *(short8*)&Bs[(ar + 64) * 40 + ac] = *(const short8*)&Bt[bBase + (size_t)64 * K + k0];
        __syncthreads();
        short8 af[4], bfr[4];
        #pragma unroll
        for (int i = 0; i < 4; i++) af[i]  = *(const short8*)&As[(wm + i * 16 + l16) * 40 + quad * 8];
        #pragma unroll
        for (int i = 0; i < 4; i++) bfr[i] = *(const short8*)&Bs[(wn + i * 16 + l16) * 40 + quad * 8];
        #pragma unroll
        for (int i = 0; i < 4; i++)
            #pragma unroll
            for (int j = 0; j < 4; j++)
                acc[i][j] = __builtin_amdgcn_mfma_f32_16x16x32_bf16(af[i], bfr[j], acc[i][j], 0, 0, 0);
        __syncthreads();
    }
    #pragma unroll
    for (int i = 0; i < 4; i++) {
        #pragma unroll
        for (int j = 0; j < 4; j++) {
            const int col = n0 + wn + j * 16 + l16;
            const float bv = bias[col];
            #pragma unroll
            for (int r = 0; r < 4; r++) {
                const int row = m0 + wm + i * 16 + quad * 4 + r;
                float val = acc[i][j][r] + bv;
                if (EPI == 1) val = gelu_exact(val);
                if (EPI == 2) val += resid[(size_t)row * N + col];
                if (OUT_BF16)
                    ((__hip_bfloat16*)Cout)[(size_t)row * N + col] = __float2bfloat16(val);
                else
                    ((float*)Cout)[(size_t)row * N + col] = val;
            }
        }
    }
}

// ---------- attention: one block per (b, n, t) query row ----------
__global__ __launch_bounds__(256) void attn_kernel(const __hip_bfloat16* __restrict__ qkv,
                                                   __hip_bfloat16* __restrict__ ctx) {
    const int t = blockIdx.x, bn = blockIdx.y;
    const int b = bn >> 4, n = bn & 15;
    const int NHD = 3072;
    const __hip_bfloat16* qp    = qkv + ((size_t)(b * Tc + t)) * NHD + n * Hc;
    const __hip_bfloat16* kbase = qkv + (size_t)b * Tc * NHD + Dc + n * Hc;
    const __hip_bfloat16* vbase = kbase + Dc;
    __shared__ float qs[Hc];
    __shared__ float sc[Tc];
    __shared__ float red[4];
    __shared__ float part[4][Hc];
    const int tid = threadIdx.x;
    if (tid < Hc) qs[tid] = bf2f(qp[tid]);
    __syncthreads();
    // phase 1: scores + softcap + running max
    float lmax = -1e30f;
    const float2* qs2 = (const float2*)qs;
    for (int s = tid; s < Tc; s += 256) {
        const __hip_bfloat162* kr = (const __hip_bfloat162*)(kbase + (size_t)s * NHD);
        float d = 0.f;
        #pragma unroll
        for (int h = 0; h < Hc / 2; h++) {
            float2 kf = __bfloat1622float2(kr[h]);
            float2 qf = qs2[h];
            d += qf.x * kf.x + qf.y * kf.y;
        }
        d *= 0.125f;                                   // 1/sqrt(H)
        d = SOFTCAP * tanhf(d * (1.0f / SOFTCAP));     // logit soft cap
        sc[s] = d;
        lmax = fmaxf(lmax, d);
    }
    #pragma unroll
    for (int o = 32; o; o >>= 1) lmax = fmaxf(lmax, __shfl_down(lmax, o, 64));
    if ((tid & 63) == 0) red[tid >> 6] = lmax;
    __syncthreads();
    const float smax = fmaxf(fmaxf(red[0], red[1]), fmaxf(red[2], red[3]));
    // phase 2: exp + sum
    float lsum = 0.f;
    for (int s = tid; s < Tc; s += 256) {
        float e = expf(sc[s] - smax);
        sc[s] = e;
        lsum += e;
    }
    #pragma unroll
    for (int o = 32; o; o >>= 1) lsum += __shfl_down(lsum, o, 64);
    __syncthreads();   // everyone has read red (smax) and finished sc writes
    if ((tid & 63) == 0) red[tid >> 6] = lsum;
    __syncthreads();
    const float inv = 1.0f / (red[0] + red[1] + red[2] + red[3]);
    // phase 3: context = P @ V  (h = lane, coalesced across 64 lanes)
    const int h = tid & 63, g = tid >> 6;
    float acc0 = 0.f;
    const __hip_bfloat16* vp = vbase + h;
    for (int s = g * 512; s < (g + 1) * 512; ++s)
        acc0 += sc[s] * bf2f(vp[(size_t)s * NHD]);
    part[g][h] = acc0;
    __syncthreads();
    if (tid < Hc) {
        float rsum = (part[0][tid] + part[1][tid] + part[2][tid] + part[3][tid]) * inv;
        ctx[((size_t)(b * Tc + t)) * Dc + n * Hc + tid] = __float2bfloat16(rsum);
    }
}

extern "C" void kernel_launch(void* const* d_in, const int* in_sizes, int n_in,
                              void* d_out, int out_size, void* d_ws, size_t ws_size,
                              hipStream_t stream) {
    const float* inputs = (const float*)d_in[0];
    const float* ln1_g  = (const float*)d_in[1];
    const float* ln1_b  = (const float*)d_in[2];
    const float* wq     = (const float*)d_in[3];
    const float* bq     = (const float*)d_in[4];
    const float* wk     = (const float*)d_in[5];
    const float* bk     = (const float*)d_in[6];
    const float* wv     = (const float*)d_in[7];
    const float* bv     = (const float*)d_in[8];
    const float* wo     = (const float*)d_in[9];
    const float* bo     = (const float*)d_in[10];
    const float* ln2_g  = (const float*)d_in[11];
    const float* ln2_b  = (const float*)d_in[12];
    const float* w1     = (const float*)d_in[13];
    const float* b1     = (const float*)d_in[14];
    const float* w2     = (const float*)d_in[15];
    const float* b2     = (const float*)d_in[16];

    char* ws = (char*)d_ws;
    auto alloc = [&](size_t bytes) {
        char* p = ws;
        ws += (bytes + 255) & ~(size_t)255;
        return p;
    };
    __hip_bfloat16* wqkv_t = (__hip_bfloat16*)alloc((size_t)3072 * 1024 * 2);
    __hip_bfloat16* wo_t   = (__hip_bfloat16*)alloc((size_t)1024 * 1024 * 2);
    __hip_bfloat16* w1_t   = (__hip_bfloat16*)alloc((size_t)4096 * 1024 * 2);
    __hip_bfloat16* w2_t   = (__hip_bfloat16*)alloc((size_t)4096 * 1024 * 2);
    float*          bqkv   = (float*)alloc(3072 * 4);
    __hip_bfloat16* xn     = (__hip_bfloat16*)alloc((size_t)Mrows * 1024 * 2);
    __hip_bfloat16* qkv    = (__hip_bfloat16*)alloc((size_t)Mrows * 3072 * 2);
    __hip_bfloat16* ctx    = (__hip_bfloat16*)alloc((size_t)Mrows * 1024 * 2);
    float*          xres   = (float*)alloc((size_t)Mrows * 1024 * 4);
    // y1 aliases qkv+ctx (both dead after out-projection): 64 MB needed, 64+ MB available
    __hip_bfloat16* y1     = qkv;

    dim3 blk(256);
    // weight prep (transpose to [N,K] bf16)
    transpose_cvt<<<dim3(32, 32), blk, 0, stream>>>(wq, wqkv_t, 1024, 1024);
    transpose_cvt<<<dim3(32, 32), blk, 0, stream>>>(wk, wqkv_t + 1024 * 1024, 1024, 1024);
    transpose_cvt<<<dim3(32, 32), blk, 0, stream>>>(wv, wqkv_t + 2048 * 1024, 1024, 1024);
    transpose_cvt<<<dim3(32, 32), blk, 0, stream>>>(wo, wo_t, 1024, 1024);
    transpose_cvt<<<dim3(128, 32), blk, 0, stream>>>(w1, w1_t, 1024, 4096);
    transpose_cvt<<<dim3(32, 128), blk, 0, stream>>>(w2, w2_t, 4096, 1024);
    concat_bias<<<dim3(12), blk, 0, stream>>>(bq, bk, bv, bqkv);

    // ln1: inputs -> xn (bf16)
    ln_kernel<<<dim3(Mrows), blk, 0, stream>>>(inputs, ln1_g, ln1_b, xn);
    // qkv = xn @ wqkv + bqkv   [8192, 3072] bf16
    gemm_kernel<0, true><<<dim3(64, 24), blk, 0, stream>>>(xn, wqkv_t, bqkv, nullptr, qkv, Mrows, 3072, 1024);
    // attention -> ctx [8192, 1024] bf16
    attn_kernel<<<dim3(Tc, Bc * Nheads), blk, 0, stream>>>(qkv, ctx);
    // x_res = ctx @ wo + bo + inputs   (fp32)
    gemm_kernel<2, false><<<dim3(64, 8), blk, 0, stream>>>(ctx, wo_t, bo, inputs, xres, Mrows, 1024, 1024);
    // ln2: xres -> xn (bf16)
    ln_kernel<<<dim3(Mrows), blk, 0, stream>>>(xres, ln2_g, ln2_b, xn);
    // y1 = gelu(xn @ w1 + b1)  [8192, 4096] bf16
    gemm_kernel<1, true><<<dim3(64, 32), blk, 0, stream>>>(xn, w1_t, b1, nullptr, y1, Mrows, 4096, 1024);
    // out = y1 @ w2 + b2 + xres  (fp32)
    gemm_kernel<2, false><<<dim3(64, 8), blk, 0, stream>>>(y1, w2_t, b2, xres, (float*)d_out, Mrows, 1024, 4096);
}

// Round 2
// 801.304 us; speedup vs baseline: 9.1956x; 9.1956x over previous
//
#include <hip/hip_runtime.h>
#include <hip/hip_bf16.h>
#include <math.h>

typedef __attribute__((ext_vector_type(8))) short short8;
typedef __attribute__((ext_vector_type(4))) float f32x4;

constexpr int Bc = 4, Tc = 2048, Dc = 1024, Nheads = 16, Hc = 64, Fc = 4096;
constexpr int Mrows = Bc * Tc;          // 8192
constexpr float SOFTCAP = 50.0f;
constexpr float LNEPS = 1e-6f;

__device__ __forceinline__ float bf2f(__hip_bfloat16 x) { return __bfloat162float(x); }

__device__ __forceinline__ float gelu_exact(float x) {
    return 0.5f * x * (1.0f + erff(x * 0.70710678118654752440f));
}

// fast tanh via v_exp; input clamped so exp never overflows
__device__ __forceinline__ float fast_tanh(float x) {
    x = fminf(fmaxf(x, -15.0f), 15.0f);
    float e = __expf(2.0f * x);
    return (e - 1.0f) / (e + 1.0f);
}

// ---------- fp32 [K,N] -> bf16 [N,K] transpose+convert ----------
__global__ __launch_bounds__(256) void transpose_cvt(const float* __restrict__ src,
                                                     __hip_bfloat16* __restrict__ dst,
                                                     int K, int N) {
    __shared__ float tile[32][33];
    const int n0 = blockIdx.x * 32, k0 = blockIdx.y * 32;
    const int tx = threadIdx.x & 31, ty = threadIdx.x >> 5;   // 32 x 8
    #pragma unroll
    for (int i = 0; i < 32; i += 8)
        tile[ty + i][tx] = src[(size_t)(k0 + ty + i) * N + (n0 + tx)];
    __syncthreads();
    #pragma unroll
    for (int i = 0; i < 32; i += 8)
        dst[(size_t)(n0 + ty + i) * K + (k0 + tx)] = __float2bfloat16(tile[tx][ty + i]);
}

// ---------- concat bq,bk,bv -> [3072] ----------
__global__ void concat_bias(const float* __restrict__ bq, const float* __restrict__ bk,
                            const float* __restrict__ bv, float* __restrict__ dst) {
    int i = blockIdx.x * 256 + threadIdx.x;   // 3072 total
    float v = (i < 1024) ? bq[i] : (i < 2048 ? bk[i - 1024] : bv[i - 2048]);
    dst[i] = v;
}

// ---------- LayerNorm fp32 -> bf16 ----------
__global__ __launch_bounds__(256) void ln_kernel(const float* __restrict__ x,
                                                 const float* __restrict__ gamma,
                                                 const float* __restrict__ beta,
                                                 __hip_bfloat16* __restrict__ out) {
    __shared__ float2 red[4];
    const int row = blockIdx.x, tid = threadIdx.x;
    const float* xr = x + (size_t)row * Dc;
    float4 v = ((const float4*)xr)[tid];
    float s  = v.x + v.y + v.z + v.w;
    float ss = v.x * v.x + v.y * v.y + v.z * v.z + v.w * v.w;
    #pragma unroll
    for (int o = 32; o; o >>= 1) { s += __shfl_down(s, o, 64); ss += __shfl_down(ss, o, 64); }
    if ((tid & 63) == 0) red[tid >> 6] = make_float2(s, ss);
    __syncthreads();
    float2 r0 = red[0], r1 = red[1], r2 = red[2], r3 = red[3];
    s  = r0.x + r1.x + r2.x + r3.x;
    ss = r0.y + r1.y + r2.y + r3.y;
    const float mean = s * (1.0f / Dc);
    const float var  = ss * (1.0f / Dc) - mean * mean;
    const float inv  = rsqrtf(var + LNEPS);
    float4 g  = ((const float4*)gamma)[tid];
    float4 bb = ((const float4*)beta)[tid];
    __hip_bfloat16* orow = out + (size_t)row * Dc + tid * 4;
    orow[0] = __float2bfloat16((v.x - mean) * inv * g.x + bb.x);
    orow[1] = __float2bfloat16((v.y - mean) * inv * g.y + bb.y);
    orow[2] = __float2bfloat16((v.z - mean) * inv * g.z + bb.z);
    orow[3] = __float2bfloat16((v.w - mean) * inv * g.w + bb.w);
}

// ---------- bf16 MFMA GEMM: C[M,N] = A[M,K] * Bt[N,K]^T + bias (+gelu | +resid) ----------
// EPI: 0 = bias only, 1 = bias+gelu, 2 = bias+fp32-residual
template <int EPI, bool OUT_BF16>
__global__ __launch_bounds__(256) void gemm_kernel(
    const __hip_bfloat16* __restrict__ A, const __hip_bfloat16* __restrict__ Bt,
    const float* __restrict__ bias, const float* __restrict__ resid,
    void* __restrict__ Cout, int M, int N, int K) {
    __shared__ __align__(16) __hip_bfloat16 As[128 * 40];
    __shared__ __align__(16) __hip_bfloat16 Bs[128 * 40];
    const int tid = threadIdx.x;
    const int wave = tid >> 6, lane = tid & 63, quad = lane >> 4, l16 = lane & 15;
    const int m0 = blockIdx.x * 128, n0 = blockIdx.y * 128;
    const int wm = (wave >> 1) * 64, wn = (wave & 1) * 64;
    const int ar = tid >> 2, ac = (tid & 3) * 8;
    f32x4 acc[4][4] = {};

    const size_t aBase = (size_t)(m0 + ar) * K + ac;
    const size_t bBase = (size_t)(n0 + ar) * K + ac;
    for (int k0 = 0; k0 < K; k0 += 32) {
        *(short8*)&As[ar * 40 + ac]        = *(const short8*)&A[aBase + k0];
        *(short8*)&As[(ar + 64) * 40 + ac] = *(const short8*)&A[aBase + (size_t)64 * K + k0];
        *(short8*)&Bs[ar * 40 + ac]        = *(const short8*)&Bt[bBase + k0];
        *(short8*)&Bs[(ar + 64) * 40 + ac] = *(const short8*)&Bt[bBase + (size_t)64 * K + k0];
        __syncthreads();
        short8 af[4], bfr[4];
        #pragma unroll
        for (int i = 0; i < 4; i++) af[i]  = *(const short8*)&As[(wm + i * 16 + l16) * 40 + quad * 8];
        #pragma unroll
        for (int i = 0; i < 4; i++) bfr[i] = *(const short8*)&Bs[(wn + i * 16 + l16) * 40 + quad * 8];
        #pragma unroll
        for (int i = 0; i < 4; i++)
            #pragma unroll
            for (int j = 0; j < 4; j++)
                acc[i][j] = __builtin_amdgcn_mfma_f32_16x16x32_bf16(af[i], bfr[j], acc[i][j], 0, 0, 0);
        __syncthreads();
    }
    #pragma unroll
    for (int i = 0; i < 4; i++) {
        #pragma unroll
        for (int j = 0; j < 4; j++) {
            const int col = n0 + wn + j * 16 + l16;
            const float bv = bias[col];
            #pragma unroll
            for (int r = 0; r < 4; r++) {
                const int row = m0 + wm + i * 16 + quad * 4 + r;
                float val = acc[i][j][r] + bv;
                if (EPI == 1) val = gelu_exact(val);
                if (EPI == 2) val += resid[(size_t)row * N + col];
                if (OUT_BF16)
                    ((__hip_bfloat16*)Cout)[(size_t)row * N + col] = __float2bfloat16(val);
                else
                    ((float*)Cout)[(size_t)row * N + col] = val;
            }
        }
    }
}

// ---------- flash attention: one block per (head, 128-row Q tile) ----------
// qkv layout: [b, t, 3072] with q at n*64, k at 1024+n*64, v at 2048+n*64.
// Soft cap bounds scores to [-50,50] -> exp(s) is finite in fp32, so we use a
// FIXED softmax max of 0: no running max, no rescale, one reduction at the end.
__global__ __launch_bounds__(256) void flash_attn(const __hip_bfloat16* __restrict__ qkv,
                                                  __hip_bfloat16* __restrict__ ctx) {
    constexpr int NHD = 3072;
    constexpr int LDP = 72;                 // LDS row stride (elems): 144B, 16B-aligned
    __shared__ __align__(16) short Qs[128 * LDP];
    __shared__ __align__(16) short Ks[64 * LDP];
    __shared__ __align__(16) short Vt[64 * LDP];   // Vt[h][s]
    __shared__ __align__(16) short Ps[4 * 32 * LDP];

    const int tid = threadIdx.x;
    const int wave = tid >> 6, lane = tid & 63, quad = lane >> 4, l16 = lane & 15;
    const int t0 = blockIdx.x * 128;
    const int bb = blockIdx.y >> 4, hn = blockIdx.y & 15;
    const __hip_bfloat16* Qg = qkv + ((size_t)(bb * Tc + t0)) * NHD + hn * Hc;
    const __hip_bfloat16* Kg = qkv + (size_t)bb * Tc * NHD + Dc + hn * Hc;
    const __hip_bfloat16* Vg = Kg + Dc;

    // stage Q tile [128 x 64] once (K-major, as loaded)
    {
        const int r = tid >> 3, c = (tid & 7) * 8;
        #pragma unroll
        for (int p = 0; p < 4; ++p)
            *(short8*)&Qs[(r + p * 32) * LDP + c] =
                *(const short8*)&Qg[(size_t)(r + p * 32) * NHD + c];
    }

    const int wm = wave * 32;               // this wave's 32 Q rows within the tile
    short* Psw = Ps + wave * 32 * LDP;      // wave-private P buffer
    f32x4 o_acc[2][4] = {};                 // O[32 x 64]: i(2) x htile(4)
    float l_acc[2][4] = {};                 // row-sum accumulator per (i, r)

    for (int s0 = 0; s0 < Tc; s0 += 64) {
        __syncthreads();                    // previous iter's K/V reads done
        // stage K tile [64 x 64] K-major and V^T tile [h=64][s=64]
        {
            const int r = tid >> 3, c = (tid & 7) * 8;
            #pragma unroll
            for (int p = 0; p < 2; ++p) {
                const int s = r + p * 32;
                *(short8*)&Ks[s * LDP + c] =
                    *(const short8*)&Kg[(size_t)(s0 + s) * NHD + c];
                short8 vv = *(const short8*)&Vg[(size_t)(s0 + s) * NHD + c];
                #pragma unroll
                for (int j = 0; j < 8; ++j)
                    Vt[(c + j) * LDP + s] = ((short*)&vv)[j];
            }
        }
        __syncthreads();

        // S = Q K^T for this wave's 32 rows x 64 cols
        f32x4 s_acc[2][4] = {};
        #pragma unroll
        for (int kt = 0; kt < 2; ++kt) {
            short8 aq[2], bk_[4];
            #pragma unroll
            for (int i = 0; i < 2; ++i)
                aq[i] = *(const short8*)&Qs[(wm + i * 16 + l16) * LDP + kt * 32 + quad * 8];
            #pragma unroll
            for (int j = 0; j < 4; ++j)
                bk_[j] = *(const short8*)&Ks[(j * 16 + l16) * LDP + kt * 32 + quad * 8];
            #pragma unroll
            for (int i = 0; i < 2; ++i)
                #pragma unroll
                for (int j = 0; j < 4; ++j)
                    s_acc[i][j] = __builtin_amdgcn_mfma_f32_16x16x32_bf16(aq[i], bk_[j], s_acc[i][j], 0, 0, 0);
        }

        // softcap + exp (fixed max = 0), accumulate row sums, write P to LDS
        #pragma unroll
        for (int i = 0; i < 2; ++i) {
            #pragma unroll
            for (int j = 0; j < 4; ++j) {
                #pragma unroll
                for (int r = 0; r < 4; ++r) {
                    float v = s_acc[i][j][r] * 0.125f;              // 1/sqrt(H)
                    v = SOFTCAP * fast_tanh(v * (1.0f / SOFTCAP));  // soft cap
                    float e = __expf(v);                            // max-free: |v| <= 50
                    l_acc[i][r] += e;
                    __hip_bfloat16 h = __float2bfloat16(e);
                    Psw[(i * 16 + quad * 4 + r) * LDP + j * 16 + l16] = __builtin_bit_cast(short, h);
                }
            }
        }
        asm volatile("" ::: "memory");      // order P writes before P frag reads (wave-private)

        // O += P V   (A = P[32 x 64s], B = Vt[h][s])
        #pragma unroll
        for (int kt = 0; kt < 2; ++kt) {
            short8 ap[2], bv_[4];
            #pragma unroll
            for (int i = 0; i < 2; ++i)
                ap[i] = *(const short8*)&Psw[(i * 16 + l16) * LDP + kt * 32 + quad * 8];
            #pragma unroll
            for (int ht = 0; ht < 4; ++ht)
                bv_[ht] = *(const short8*)&Vt[(ht * 16 + l16) * LDP + kt * 32 + quad * 8];
            #pragma unroll
            for (int i = 0; i < 2; ++i)
                #pragma unroll
                for (int ht = 0; ht < 4; ++ht)
                    o_acc[i][ht] = __builtin_amdgcn_mfma_f32_16x16x32_bf16(ap[i], bv_[ht], o_acc[i][ht], 0, 0, 0);
        }
    }

    // final row-sum reduction across the 16 lanes of each row, then normalize+store
    float linv[2][4];
    #pragma unroll
    for (int i = 0; i < 2; ++i)
        #pragma unroll
        for (int r = 0; r < 4; ++r) {
            float l = l_acc[i][r];
            l += __shfl_xor(l, 1, 64);
            l += __shfl_xor(l, 2, 64);
            l += __shfl_xor(l, 4, 64);
            l += __shfl_xor(l, 8, 64);
            linv[i][r] = 1.0f / l;
        }
    #pragma unroll
    for (int i = 0; i < 2; ++i)
        #pragma unroll
        for (int ht = 0; ht < 4; ++ht)
            #pragma unroll
            for (int r = 0; r < 4; ++r) {
                const int row = t0 + wm + i * 16 + quad * 4 + r;
                const int col = hn * Hc + ht * 16 + l16;
                ctx[((size_t)(bb * Tc + row)) * Dc + col] =
                    __float2bfloat16(o_acc[i][ht][r] * linv[i][r]);
            }
}

extern "C" void kernel_launch(void* const* d_in, const int* in_sizes, int n_in,
                              void* d_out, int out_size, void* d_ws, size_t ws_size,
                              hipStream_t stream) {
    const float* inputs = (const float*)d_in[0];
    const float* ln1_g  = (const float*)d_in[1];
    const float* ln1_b  = (const float*)d_in[2];
    const float* wq     = (const float*)d_in[3];
    const float* bq     = (const float*)d_in[4];
    const float* wk     = (const float*)d_in[5];
    const float* bk     = (const float*)d_in[6];
    const float* wv     = (const float*)d_in[7];
    const float* bv     = (const float*)d_in[8];
    const float* wo     = (const float*)d_in[9];
    const float* bo     = (const float*)d_in[10];
    const float* ln2_g  = (const float*)d_in[11];
    const float* ln2_b  = (const float*)d_in[12];
    const float* w1     = (const float*)d_in[13];
    const float* b1     = (const float*)d_in[14];
    const float* w2     = (const float*)d_in[15];
    const float* b2     = (const float*)d_in[16];

    char* ws = (char*)d_ws;
    auto alloc = [&](size_t bytes) {
        char* p = ws;
        ws += (bytes + 255) & ~(size_t)255;
        return p;
    };
    __hip_bfloat16* wqkv_t = (__hip_bfloat16*)alloc((size_t)3072 * 1024 * 2);
    __hip_bfloat16* wo_t   = (__hip_bfloat16*)alloc((size_t)1024 * 1024 * 2);
    __hip_bfloat16* w1_t   = (__hip_bfloat16*)alloc((size_t)4096 * 1024 * 2);
    __hip_bfloat16* w2_t   = (__hip_bfloat16*)alloc((size_t)4096 * 1024 * 2);
    float*          bqkv   = (float*)alloc(3072 * 4);
    __hip_bfloat16* xn     = (__hip_bfloat16*)alloc((size_t)Mrows * 1024 * 2);
    __hip_bfloat16* qkv    = (__hip_bfloat16*)alloc((size_t)Mrows * 3072 * 2);
    __hip_bfloat16* ctx    = (__hip_bfloat16*)alloc((size_t)Mrows * 1024 * 2);
    float*          xres   = (float*)alloc((size_t)Mrows * 1024 * 4);
    __hip_bfloat16* y1     = qkv;   // alias: qkv dead after attention+out-proj

    dim3 blk(256);
    transpose_cvt<<<dim3(32, 32), blk, 0, stream>>>(wq, wqkv_t, 1024, 1024);
    transpose_cvt<<<dim3(32, 32), blk, 0, stream>>>(wk, wqkv_t + 1024 * 1024, 1024, 1024);
    transpose_cvt<<<dim3(32, 32), blk, 0, stream>>>(wv, wqkv_t + 2048 * 1024, 1024, 1024);
    transpose_cvt<<<dim3(32, 32), blk, 0, stream>>>(wo, wo_t, 1024, 1024);
    transpose_cvt<<<dim3(128, 32), blk, 0, stream>>>(w1, w1_t, 1024, 4096);
    transpose_cvt<<<dim3(32, 128), blk, 0, stream>>>(w2, w2_t, 4096, 1024);
    concat_bias<<<dim3(12), blk, 0, stream>>>(bq, bk, bv, bqkv);

    ln_kernel<<<dim3(Mrows), blk, 0, stream>>>(inputs, ln1_g, ln1_b, xn);
    gemm_kernel<0, true><<<dim3(64, 24), blk, 0, stream>>>(xn, wqkv_t, bqkv, nullptr, qkv, Mrows, 3072, 1024);
    flash_attn<<<dim3(Tc / 128, Bc * Nheads), blk, 0, stream>>>(qkv, ctx);
    gemm_kernel<2, false><<<dim3(64, 8), blk, 0, stream>>>(ctx, wo_t, bo, inputs, xres, Mrows, 1024, 1024);
    ln_kernel<<<dim3(Mrows), blk, 0, stream>>>(xres, ln2_g, ln2_b, xn);
    gemm_kernel<1, true><<<dim3(64, 32), blk, 0, stream>>>(xn, w1_t, b1, nullptr, y1, Mrows, 4096, 1024);
    gemm_kernel<2, false><<<dim3(64, 8), blk, 0, stream>>>(y1, w2_t, b2, xres, (float*)d_out, Mrows, 1024, 4096);
}

// Round 3
// 631.267 us; speedup vs baseline: 11.6725x; 1.2694x over previous
//
#include <hip/hip_runtime.h>
#include <hip/hip_bf16.h>
#include <math.h>

typedef __attribute__((ext_vector_type(8))) short short8;
typedef __attribute__((ext_vector_type(4))) float f32x4;

#define GAS __attribute__((address_space(1)))
#define LAS __attribute__((address_space(3)))

__device__ __forceinline__ LAS void* to_lds(void* p) {
    return (LAS void*)(unsigned)(uintptr_t)p;
}

constexpr int Bc = 4, Tc = 2048, Dc = 1024, Nheads = 16, Hc = 64, Fc = 4096;
constexpr int Mrows = Bc * Tc;          // 8192
constexpr float LNEPS = 1e-6f;

__device__ __forceinline__ float gelu_exact(float x) {
    return 0.5f * x * (1.0f + erff(x * 0.70710678118654752440f));
}

// ---------- fp32 [K,N] -> bf16 [N,K] transpose+convert ----------
__global__ __launch_bounds__(256) void transpose_cvt(const float* __restrict__ src,
                                                     __hip_bfloat16* __restrict__ dst,
                                                     int K, int N) {
    __shared__ float tile[32][33];
    const int n0 = blockIdx.x * 32, k0 = blockIdx.y * 32;
    const int tx = threadIdx.x & 31, ty = threadIdx.x >> 5;   // 32 x 8
    #pragma unroll
    for (int i = 0; i < 32; i += 8)
        tile[ty + i][tx] = src[(size_t)(k0 + ty + i) * N + (n0 + tx)];
    __syncthreads();
    #pragma unroll
    for (int i = 0; i < 32; i += 8)
        dst[(size_t)(n0 + ty + i) * K + (k0 + tx)] = __float2bfloat16(tile[tx][ty + i]);
}

// ---------- concat bq,bk,bv -> [3072] ----------
__global__ void concat_bias(const float* __restrict__ bq, const float* __restrict__ bk,
                            const float* __restrict__ bv, float* __restrict__ dst) {
    int i = blockIdx.x * 256 + threadIdx.x;   // 3072 total
    float v = (i < 1024) ? bq[i] : (i < 2048 ? bk[i - 1024] : bv[i - 2048]);
    dst[i] = v;
}

// ---------- LayerNorm fp32 -> bf16 ----------
__global__ __launch_bounds__(256) void ln_kernel(const float* __restrict__ x,
                                                 const float* __restrict__ gamma,
                                                 const float* __restrict__ beta,
                                                 __hip_bfloat16* __restrict__ out) {
    __shared__ float2 red[4];
    const int row = blockIdx.x, tid = threadIdx.x;
    const float* xr = x + (size_t)row * Dc;
    float4 v = ((const float4*)xr)[tid];
    float s  = v.x + v.y + v.z + v.w;
    float ss = v.x * v.x + v.y * v.y + v.z * v.z + v.w * v.w;
    #pragma unroll
    for (int o = 32; o; o >>= 1) { s += __shfl_down(s, o, 64); ss += __shfl_down(ss, o, 64); }
    if ((tid & 63) == 0) red[tid >> 6] = make_float2(s, ss);
    __syncthreads();
    float2 r0 = red[0], r1 = red[1], r2 = red[2], r3 = red[3];
    s  = r0.x + r1.x + r2.x + r3.x;
    ss = r0.y + r1.y + r2.y + r3.y;
    const float mean = s * (1.0f / Dc);
    const float var  = ss * (1.0f / Dc) - mean * mean;
    const float inv  = rsqrtf(var + LNEPS);
    float4 g  = ((const float4*)gamma)[tid];
    float4 bb = ((const float4*)beta)[tid];
    __hip_bfloat16* orow = out + (size_t)row * Dc + tid * 4;
    orow[0] = __float2bfloat16((v.x - mean) * inv * g.x + bb.x);
    orow[1] = __float2bfloat16((v.y - mean) * inv * g.y + bb.y);
    orow[2] = __float2bfloat16((v.z - mean) * inv * g.z + bb.z);
    orow[3] = __float2bfloat16((v.w - mean) * inv * g.w + bb.w);
}

// ---------- bf16 MFMA GEMM (m97 structure): C = A[M,K] * Bt[N,K]^T + bias ----------
// EPI: 0 = bias only, 1 = bias+gelu, 2 = bias+fp32-residual
template <int EPI, bool OUT_BF16>
__global__ __launch_bounds__(256) void gemm_kernel(
    const __hip_bfloat16* __restrict__ A, const __hip_bfloat16* __restrict__ Bt,
    const float* __restrict__ bias, const float* __restrict__ resid,
    void* __restrict__ Cout, int M, int N, int K) {
    // unpadded [128][32]: REQUIRED for global_load_lds lane-contiguity
    __shared__ __align__(16) short As[128 * 32];
    __shared__ __align__(16) short Bs[128 * 32];
    const int tid = threadIdx.x;
    const int wave = tid >> 6, lane = tid & 63, quad = lane >> 4, l16 = lane & 15;
    const int m0 = blockIdx.x * 128, n0 = blockIdx.y * 128;
    const int wm = (wave >> 1) * 64, wn = (wave & 1) * 64;
    f32x4 acc[4][4] = {};

    // staging: wave w covers rows [16w,16w+16) and [64+16w, 64+16w+16)
    const int srow = wave * 16 + (lane >> 2);
    const int scol = (lane & 3) * 8;
    const short* aSrc0 = (const short*)A  + (size_t)(m0 + srow) * K + scol;
    const short* aSrc1 = aSrc0 + (size_t)64 * K;
    const short* bSrc0 = (const short*)Bt + (size_t)(n0 + srow) * K + scol;
    const short* bSrc1 = bSrc0 + (size_t)64 * K;
    LAS void* ldsA0 = to_lds(&As[(wave * 16) * 32]);
    LAS void* ldsA1 = to_lds(&As[(64 + wave * 16) * 32]);
    LAS void* ldsB0 = to_lds(&Bs[(wave * 16) * 32]);
    LAS void* ldsB1 = to_lds(&Bs[(64 + wave * 16) * 32]);

    for (int k0 = 0; k0 < K; k0 += 32) {
        __builtin_amdgcn_global_load_lds((const GAS void*)(aSrc0 + k0), ldsA0, 16, 0, 0);
        __builtin_amdgcn_global_load_lds((const GAS void*)(aSrc1 + k0), ldsA1, 16, 0, 0);
        __builtin_amdgcn_global_load_lds((const GAS void*)(bSrc0 + k0), ldsB0, 16, 0, 0);
        __builtin_amdgcn_global_load_lds((const GAS void*)(bSrc1 + k0), ldsB1, 16, 0, 0);
        __syncthreads();
        short8 af[4], bfr[4];
        #pragma unroll
        for (int i = 0; i < 4; i++) af[i]  = *(const short8*)&As[(wm + i * 16 + l16) * 32 + quad * 8];
        #pragma unroll
        for (int i = 0; i < 4; i++) bfr[i] = *(const short8*)&Bs[(wn + i * 16 + l16) * 32 + quad * 8];
        #pragma unroll
        for (int i = 0; i < 4; i++)
            #pragma unroll
            for (int j = 0; j < 4; j++)
                acc[i][j] = __builtin_amdgcn_mfma_f32_16x16x32_bf16(af[i], bfr[j], acc[i][j], 0, 0, 0);
        __syncthreads();
    }
    #pragma unroll
    for (int i = 0; i < 4; i++) {
        #pragma unroll
        for (int j = 0; j < 4; j++) {
            const int col = n0 + wn + j * 16 + l16;
            const float bv = bias[col];
            #pragma unroll
            for (int r = 0; r < 4; r++) {
                const int row = m0 + wm + i * 16 + quad * 4 + r;
                float val = acc[i][j][r] + bv;
                if (EPI == 1) val = gelu_exact(val);
                if (EPI == 2) val += resid[(size_t)row * N + col];
                if (OUT_BF16)
                    ((__hip_bfloat16*)Cout)[(size_t)row * N + col] = __float2bfloat16(val);
                else
                    ((float*)Cout)[(size_t)row * N + col] = val;
            }
        }
    }
}

// ---------- flash attention: one block per (head, 128-row Q tile) ----------
// Fixed softmax max = 0 (soft cap bounds scores to [-50,50]).
// Q A-frags loaded directly from global (loop-invariant, hoisted).
// Vt and Ps XOR-swizzled to kill bank conflicts.
__global__ __launch_bounds__(256, 4) void flash_attn(const __hip_bfloat16* __restrict__ qkv,
                                                     __hip_bfloat16* __restrict__ ctx) {
    constexpr int NHD = 3072;
    constexpr int LQ = 72;                  // K/V LDS stride (elems)
    constexpr int LP = 40;                  // P LDS stride (elems), 32 cols/half
    __shared__ __align__(16) short Ks[64 * LQ];      // 9216 B
    __shared__ __align__(16) short Vt[64 * LQ];      // 9216 B, col swizzled
    __shared__ __align__(16) short Ps[4 * 32 * LP];  // 10240 B

    const int tid = threadIdx.x;
    const int wave = tid >> 6, lane = tid & 63, quad = lane >> 4, l16 = lane & 15;
    const int t0 = blockIdx.x * 128;
    const int bb = blockIdx.y >> 4, hn = blockIdx.y & 15;
    const __hip_bfloat16* Qg = qkv + ((size_t)(bb * Tc + t0)) * NHD + hn * Hc;
    const __hip_bfloat16* Kg = qkv + (size_t)bb * Tc * NHD + Dc + hn * Hc;
    const __hip_bfloat16* Vg = Kg + Dc;

    const int wm = wave * 32;
    short* Psw = Ps + wave * 32 * LP;

    // hoisted Q A-fragments (global, 16B aligned): A[m = wm+i*16+l16][k = kt*32+quad*8 ..]
    short8 aq[2][2];
    #pragma unroll
    for (int kt = 0; kt < 2; ++kt)
        #pragma unroll
        for (int i = 0; i < 2; ++i)
            aq[kt][i] = *(const short8*)&Qg[(size_t)(wm + i * 16 + l16) * NHD + kt * 32 + quad * 8];

    f32x4 o_acc[2][4] = {};
    float l_acc[2][4] = {};
    const int swzA = (l16 >> 2) * 8;        // Ps read swizzle

    for (int s0 = 0; s0 < Tc; s0 += 64) {
        __syncthreads();                    // prev iter K/V reads done
        {   // stage K [s][h] and V^T [h][s^c] (swizzled)
            const int r = tid >> 3, c = (tid & 7) * 8;
            #pragma unroll
            for (int p = 0; p < 2; ++p) {
                const int s = r + p * 32;
                *(short8*)&Ks[s * LQ + c] = *(const short8*)&Kg[(size_t)(s0 + s) * NHD + c];
                short8 vv = *(const short8*)&Vg[(size_t)(s0 + s) * NHD + c];
                #pragma unroll
                for (int j = 0; j < 8; ++j)
                    Vt[(c + j) * LQ + (s ^ c)] = ((short*)&vv)[j];
            }
        }
        __syncthreads();

        // S = Q K^T  (contraction over h via kt)
        f32x4 s_acc[2][4] = {};
        #pragma unroll
        for (int kt = 0; kt < 2; ++kt) {
            short8 bk_[4];
            #pragma unroll
            for (int j = 0; j < 4; ++j)
                bk_[j] = *(const short8*)&Ks[(j * 16 + l16) * LQ + kt * 32 + quad * 8];
            #pragma unroll
            for (int i = 0; i < 2; ++i)
                #pragma unroll
                for (int j = 0; j < 4; ++j)
                    s_acc[i][j] = __builtin_amdgcn_mfma_f32_16x16x32_bf16(aq[kt][i], bk_[j], s_acc[i][j], 0, 0, 0);
        }

        // per 32-col half: softcap+exp -> Ps, then O += P V
        #pragma unroll
        for (int kt = 0; kt < 2; ++kt) {
            asm volatile("" ::: "memory");
            #pragma unroll
            for (int i = 0; i < 2; ++i)
                #pragma unroll
                for (int j2 = 0; j2 < 2; ++j2)
                    #pragma unroll
                    for (int r = 0; r < 4; ++r) {
                        const float s = s_acc[i][2 * kt + j2][r];
                        // p = exp(50*tanh((s/8)/50)); tanh = 1 - 2/(u+1), u = e^{s/200}
                        const float u  = __expf(s * 0.005f);
                        const float rr = __builtin_amdgcn_rcpf(u + 1.0f);
                        const float p  = __expf(fmaf(rr, -100.0f, 50.0f));
                        l_acc[i][r] += p;
                        __hip_bfloat16 h = __float2bfloat16(p);
                        Psw[(i * 16 + quad * 4 + r) * LP + ((j2 * 16 + l16) ^ (quad * 8))] =
                            __builtin_bit_cast(short, h);
                    }
            asm volatile("" ::: "memory");  // order P writes before P reads (wave-private)
            short8 ap[2], bv_[4];
            #pragma unroll
            for (int i = 0; i < 2; ++i)
                ap[i] = *(const short8*)&Psw[(i * 16 + l16) * LP + ((quad * 8) ^ swzA)];
            #pragma unroll
            for (int ht = 0; ht < 4; ++ht) {
                const int swzV = ht * 16 + (l16 >> 3) * 8;
                bv_[ht] = *(const short8*)&Vt[(ht * 16 + l16) * LQ + ((kt * 32 + quad * 8) ^ swzV)];
            }
            #pragma unroll
            for (int i = 0; i < 2; ++i)
                #pragma unroll
                for (int ht = 0; ht < 4; ++ht)
                    o_acc[i][ht] = __builtin_amdgcn_mfma_f32_16x16x32_bf16(ap[i], bv_[ht], o_acc[i][ht], 0, 0, 0);
            asm volatile("" ::: "memory");  // order P reads before next half's writes
        }
    }

    // row-sum reduce over the 16 lanes of each row, normalize, store
    float linv[2][4];
    #pragma unroll
    for (int i = 0; i < 2; ++i)
        #pragma unroll
        for (int r = 0; r < 4; ++r) {
            float l = l_acc[i][r];
            l += __shfl_xor(l, 1, 64);
            l += __shfl_xor(l, 2, 64);
            l += __shfl_xor(l, 4, 64);
            l += __shfl_xor(l, 8, 64);
            linv[i][r] = 1.0f / l;
        }
    #pragma unroll
    for (int i = 0; i < 2; ++i)
        #pragma unroll
        for (int ht = 0; ht < 4; ++ht)
            #pragma unroll
            for (int r = 0; r < 4; ++r) {
                const int row = t0 + wm + i * 16 + quad * 4 + r;
                const int col = hn * Hc + ht * 16 + l16;
                ctx[((size_t)(bb * Tc + row)) * Dc + col] =
                    __float2bfloat16(o_acc[i][ht][r] * linv[i][r]);
            }
}

extern "C" void kernel_launch(void* const* d_in, const int* in_sizes, int n_in,
                              void* d_out, int out_size, void* d_ws, size_t ws_size,
                              hipStream_t stream) {
    const float* inputs = (const float*)d_in[0];
    const float* ln1_g  = (const float*)d_in[1];
    const float* ln1_b  = (const float*)d_in[2];
    const float* wq     = (const float*)d_in[3];
    const float* bq     = (const float*)d_in[4];
    const float* wk     = (const float*)d_in[5];
    const float* bk     = (const float*)d_in[6];
    const float* wv     = (const float*)d_in[7];
    const float* bv     = (const float*)d_in[8];
    const float* wo     = (const float*)d_in[9];
    const float* bo     = (const float*)d_in[10];
    const float* ln2_g  = (const float*)d_in[11];
    const float* ln2_b  = (const float*)d_in[12];
    const float* w1     = (const float*)d_in[13];
    const float* b1     = (const float*)d_in[14];
    const float* w2     = (const float*)d_in[15];
    const float* b2     = (const float*)d_in[16];

    char* ws = (char*)d_ws;
    auto alloc = [&](size_t bytes) {
        char* p = ws;
        ws += (bytes + 255) & ~(size_t)255;
        return p;
    };
    __hip_bfloat16* wqkv_t = (__hip_bfloat16*)alloc((size_t)3072 * 1024 * 2);
    __hip_bfloat16* wo_t   = (__hip_bfloat16*)alloc((size_t)1024 * 1024 * 2);
    __hip_bfloat16* w1_t   = (__hip_bfloat16*)alloc((size_t)4096 * 1024 * 2);
    __hip_bfloat16* w2_t   = (__hip_bfloat16*)alloc((size_t)4096 * 1024 * 2);
    float*          bqkv   = (float*)alloc(3072 * 4);
    __hip_bfloat16* xn     = (__hip_bfloat16*)alloc((size_t)Mrows * 1024 * 2);
    __hip_bfloat16* qkv    = (__hip_bfloat16*)alloc((size_t)Mrows * 3072 * 2);
    __hip_bfloat16* ctx    = (__hip_bfloat16*)alloc((size_t)Mrows * 1024 * 2);
    float*          xres   = (float*)alloc((size_t)Mrows * 1024 * 4);
    __hip_bfloat16* y1     = qkv;   // alias: qkv dead after attention+out-proj

    dim3 blk(256);
    transpose_cvt<<<dim3(32, 32), blk, 0, stream>>>(wq, wqkv_t, 1024, 1024);
    transpose_cvt<<<dim3(32, 32), blk, 0, stream>>>(wk, wqkv_t + 1024 * 1024, 1024, 1024);
    transpose_cvt<<<dim3(32, 32), blk, 0, stream>>>(wv, wqkv_t + 2048 * 1024, 1024, 1024);
    transpose_cvt<<<dim3(32, 32), blk, 0, stream>>>(wo, wo_t, 1024, 1024);
    transpose_cvt<<<dim3(128, 32), blk, 0, stream>>>(w1, w1_t, 1024, 4096);
    transpose_cvt<<<dim3(32, 128), blk, 0, stream>>>(w2, w2_t, 4096, 1024);
    concat_bias<<<dim3(12), blk, 0, stream>>>(bq, bk, bv, bqkv);

    ln_kernel<<<dim3(Mrows), blk, 0, stream>>>(inputs, ln1_g, ln1_b, xn);
    gemm_kernel<0, true><<<dim3(64, 24), blk, 0, stream>>>(xn, wqkv_t, bqkv, nullptr, qkv, Mrows, 3072, 1024);
    flash_attn<<<dim3(Tc / 128, Bc * Nheads), blk, 0, stream>>>(qkv, ctx);
    gemm_kernel<2, false><<<dim3(64, 8), blk, 0, stream>>>(ctx, wo_t, bo, inputs, xres, Mrows, 1024, 1024);
    ln_kernel<<<dim3(Mrows), blk, 0, stream>>>(xres, ln2_g, ln2_b, xn);
    gemm_kernel<1, true><<<dim3(64, 32), blk, 0, stream>>>(xn, w1_t, b1, nullptr, y1, Mrows, 4096, 1024);
    gemm_kernel<2, false><<<dim3(64, 8), blk, 0, stream>>>(y1, w2_t, b2, xres, (float*)d_out, Mrows, 1024, 4096);
}